// Round 6
// baseline (2017.753 us; speedup 1.0000x reference)
//
#include <hip/hip_runtime.h>

#define B_ 256
#define T_ 512
#define H_ 512
#define P_ 128
#define G4 2048   // 4*H

typedef __attribute__((ext_vector_type(8))) _Float16 h8_t;
typedef __attribute__((ext_vector_type(4))) float floatx4;

__device__ __forceinline__ float sigm(float x){ return 1.0f / (1.0f + __expf(-x)); }
__device__ __forceinline__ float tanh_(float x){ return 2.0f / (1.0f + __expf(-2.0f*x)) - 1.0f; }
__device__ __forceinline__ unsigned short f2h(float f){
  union { _Float16 h; unsigned short u; } c; c.h = (_Float16)f; return c.u;
}
__device__ __forceinline__ float wredsum(float v){
  #pragma unroll
  for (int off = 32; off; off >>= 1) v += __shfl_xor(v, off, 64);
  return v;
}

// Pack enc_Whh (2048x512 fp32 row-major [gate_col][k]) into fp16 MFMA B-frag
// order. tile = (cg*4 + w)*2 + ct; element = tile*8192 + kt*512 + lane*8 + e.
// In-tile col = q*4 + dhc  ->  Whh row = q*512 + cg*32 + w*8 + ct*4 + dhc
// k = kt*32 + (lane>>4)*8 + e
__global__ __launch_bounds__(256) void pack_w(const float* __restrict__ Whh,
                                              unsigned short* __restrict__ Wp){
  int p8   = blockIdx.x * 256 + threadIdx.x;   // 0..131071
  int lane = p8 & 63;
  int kt   = (p8 >> 6) & 15;
  int ct   = (p8 >> 10) & 1;
  int w    = (p8 >> 11) & 3;
  int cg   = (p8 >> 13) & 15;
  int q    = (lane & 15) >> 2, dhc = lane & 3;
  int col  = q*512 + cg*32 + w*8 + ct*4 + dhc;
  int k0   = kt*32 + (lane >> 4)*8;
  const float* s = Whh + (size_t)col * H_ + k0;
  unsigned short v[8];
  #pragma unroll
  for (int e = 0; e < 8; e++) v[e] = f2h(s[e]);
  *(uint4*)(Wp + (size_t)p8 * 8) = *(const uint4*)v;
}

// Persistent encoder, 2-cohort pipelined: 256 blocks (16 groups x 16 cg),
// 4 waves. Block (g,cg): cohort A rows g*8..+7, cohort B rows 128+g*8..+7,
// hc cols cg*32..+31. Phases alternate A/B so each cohort's exchange
// latency hides under the other cohort's compute. Exchange: self-tagging
// u64 {tag | 2 x fp16} via relaxed agent RMW (store) + parallel-retry poll.
__global__ __launch_bounds__(256) void enc_persist(
    const unsigned short* __restrict__ Wp,
    const float* __restrict__ x,
    const float* __restrict__ Wih,
    const float* __restrict__ bih,
    const float* __restrict__ bhh,
    unsigned long long* __restrict__ X,   // [2 parity][256 rows][256 cp] u64
    float* __restrict__ hfp,
    float* __restrict__ cfin,
    float* __restrict__ G,
    int zf)
{
  __shared__ float x_lds[16][512];      // 32 KB (rows 0-7 = A, 8-15 = B)
  __shared__ uint4 A_lds4[1024];        // 16 KB, XOR-swizzled fp16 A tile
  __shared__ float Sg[4][16][33];       // 8448 B
  __shared__ char pad_[26000];          // total 83.6 KB > 80 KB => 1 block/CU

  char* A_lds = (char*)A_lds4;
  const int bid = blockIdx.x;
  const int g = bid >> 4, cg = bid & 15;
  const int tid = threadIdx.x;
  const int lane = tid & 63, wv = tid >> 6;
  const int rA = g*8, rB = 128 + g*8;

  if (zf){ pad_[tid] = (char)Wih[tid]; if (!tid) A_lds[0] = pad_[128]; }

  // ---- W fragments into registers (once): 128 regs/wave, shared by cohorts
  h8_t wreg[2][16];
  {
    const unsigned short* wb = Wp + (size_t)((cg*4 + wv)*2) * 8192;
    #pragma unroll
    for (int ct = 0; ct < 2; ct++)
      #pragma unroll
      for (int kt = 0; kt < 16; kt++)
        wreg[ct][kt] = *(const h8_t*)(wb + (ct*16 + kt)*512 + lane*8);
  }
  // ---- stage x rows (once): 8 A-rows then 8 B-rows
  #pragma unroll
  for (int i = 0; i < 8; i++){
    int idx = tid + i*256;            // 0..2047
    int r = idx >> 7, c4 = (idx & 127)*4;
    int grow = (r < 8) ? (rA + r) : (rB + r - 8);
    *(float4*)&x_lds[r][c4] = *(const float4*)&x[(size_t)grow*T_ + c4];
  }
  // ---- zero A_lds rows 8..15 (MFMA reads 16 rows; only 0..7 are real)
  {
    uint4 z = {0,0,0,0};
    *(uint4*)(A_lds + 8192 + tid*32)      = z;
    *(uint4*)(A_lds + 8192 + tid*32 + 16) = z;
  }

  // ---- per-thread役: one (row, hc): erow 0..7, hc 0..31 (also staging map)
  const int erow = tid >> 5, hc = tid & 31;
  const int hcg  = cg*32 + hc;
  float wih[4], bs[4];
  #pragma unroll
  for (int q = 0; q < 4; q++){
    wih[q] = Wih[q*512 + hcg];
    bs[q]  = bih[q*512 + hcg] + bhh[q*512 + hcg];
  }
  float crA = 0.f, crB = 0.f;

  // staging: thread owns row erow, colpairs hc + j*32 (j=0..7)
  int lws[8];
  #pragma unroll
  for (int j = 0; j < 8; j++){
    int cp = hc + j*32;
    lws[j] = erow*1024 + ((cp*4) ^ ((erow & 7) << 4));
  }
  const size_t XrowA = (size_t)(rA + erow)*256 + hc;
  const size_t XrowB = (size_t)(rB + erow)*256 + hc;
  const size_t pA = (size_t)(rA + erow)*256 + cg*16 + (hc >> 1);
  const size_t pB = (size_t)(rB + erow)*256 + cg*16 + (hc >> 1);
  const int arow = lane & 15, ahalf = lane >> 4;
  const int rxor = (arow & 7) << 4;

  auto phase = [&](int t, int xrow0, size_t Xrow, size_t pidx, int grow,
                   float& cr) {
    // ---- acquire h(t-1): buffer (t+1)&1, tag == t
    unsigned long long* Xb = X + (size_t)((t+1)&1) * 65536;
    const unsigned wtag = (unsigned)t;
    unsigned pend = 0xFFu;
    do {
      unsigned long long tmp[8];
      #pragma unroll
      for (int j = 0; j < 8; j++)
        if (pend & (1u << j))
          tmp[j] = __hip_atomic_load(Xb + Xrow + j*32, __ATOMIC_RELAXED,
                                     __HIP_MEMORY_SCOPE_AGENT);
      unsigned np = 0u;
      #pragma unroll
      for (int j = 0; j < 8; j++){
        if (pend & (1u << j)){
          if ((unsigned)(tmp[j] >> 32) == wtag)
            *(unsigned*)(A_lds + lws[j]) = (unsigned)tmp[j];
          else
            np |= 1u << j;
        }
      }
      pend = np;
      if (pend) __builtin_amdgcn_s_sleep(1);
    } while (pend);
    __syncthreads();

    floatx4 acc0 = {0,0,0,0}, acc1 = {0,0,0,0};
    h8_t a[16];
    #pragma unroll
    for (int kt = 0; kt < 16; kt++)
      a[kt] = *(const h8_t*)(A_lds + arow*1024 + ((kt*64 + ahalf*16) ^ rxor));
    #pragma unroll
    for (int kt = 0; kt < 16; kt++){
      acc0 = __builtin_amdgcn_mfma_f32_16x16x32_f16(a[kt], wreg[0][kt], acc0, 0,0,0);
      acc1 = __builtin_amdgcn_mfma_f32_16x16x32_f16(a[kt], wreg[1][kt], acc1, 0,0,0);
    }
    // C/D: col = lane&15 (= q*4+dhc), row = (lane>>4)*4 + r
    #pragma unroll
    for (int r = 0; r < 4; r++){
      int srow = ahalf*4 + r;
      int q = (lane & 15) >> 2, dhc = lane & 3;
      Sg[q][srow][wv*8 + dhc]     = acc0[r];
      Sg[q][srow][wv*8 + 4 + dhc] = acc1[r];
    }
    __syncthreads();

    if (t == T_){   // Gconst = h(511)@Whh^T + bsum
      #pragma unroll
      for (int q = 0; q < 4; q++)
        G[(size_t)grow*G4 + q*512 + hcg] = Sg[q][erow][hc] + bs[q];
      return;
    }

    const float xb = x_lds[xrow0 + erow][t];
    float pi = Sg[0][erow][hc] + xb*wih[0] + bs[0];
    float pf = Sg[1][erow][hc] + xb*wih[1] + bs[1];
    float pg = Sg[2][erow][hc] + xb*wih[2] + bs[2];
    float po = Sg[3][erow][hc] + xb*wih[3] + bs[3];
    float c2 = sigm(pf)*cr + sigm(pi)*tanh_(pg);
    float h2 = sigm(po)*tanh_(c2);
    cr = c2;
    if (t == T_-1){
      hfp [(size_t)grow*512 + hcg] = h2;
      cfin[(size_t)grow*512 + hcg] = c2;
    }
    float hо = __shfl_xor(h2, 1);
    if (!(lane & 1)){
      unsigned pay = (unsigned)f2h(h2) | ((unsigned)f2h(hо) << 16);
      unsigned long long wo = ((unsigned long long)(t + 1) << 32) | pay;
      (void)__hip_atomic_exchange(X + (size_t)(t & 1)*65536 + pidx, wo,
                                  __ATOMIC_RELAXED, __HIP_MEMORY_SCOPE_AGENT);
    }
  };

  for (int t = 0; t <= T_; t++){
    phase(t, 0, XrowA, pA, rA + erow, crA);   // cohort A
    phase(t, 8, XrowB, pB, rB + erow, crB);   // cohort B
  }
}

// Decoder: scalar recurrence per batch row, one wave per row, zero syncs.
__global__ __launch_bounds__(256) void decoder(
    const float* __restrict__ G, const float* __restrict__ c,
    const float* __restrict__ hfp, const float* __restrict__ Wih,
    const float* __restrict__ dW, const float* __restrict__ db,
    float* __restrict__ out)
{
  const int row  = blockIdx.x * 4 + (threadIdx.x >> 6);
  const int lane = threadIdx.x & 63;
  float Gr[4][8], wr[4][8], cc[8], wd[8];
  float p = 0.f;
  #pragma unroll
  for (int k = 0; k < 8; k++){
    int j = lane + k*64;
    cc[k] = c[(size_t)row*H_ + j];
    wd[k] = dW[j];
    #pragma unroll
    for (int q = 0; q < 4; q++){
      Gr[q][k] = G[(size_t)row*G4 + q*512 + j];
      wr[q][k] = Wih[q*512 + j];
    }
    p += hfp[(size_t)row*H_ + j] * wd[k];
  }
  const float bias = db[0];
  float y = wredsum(p) + bias;
  for (int tt = 0; tt < P_; tt++){
    if (lane == 0) out[(size_t)row*P_ + tt] = y;
    if (tt == P_-1) break;
    float pp = 0.f;
    #pragma unroll
    for (int k = 0; k < 8; k++){
      float i_ = sigm (y*wr[0][k] + Gr[0][k]);
      float f_ = sigm (y*wr[1][k] + Gr[1][k]);
      float g_ = tanh_(y*wr[2][k] + Gr[2][k]);
      float o_ = sigm (y*wr[3][k] + Gr[3][k]);
      float c2 = f_*cc[k] + i_*g_;
      pp += o_*tanh_(c2)*wd[k];
    }
    y = wredsum(pp) + bias;
  }
}

extern "C" void kernel_launch(void* const* d_in, const int* in_sizes, int n_in,
                              void* d_out, int out_size, void* d_ws, size_t ws_size,
                              hipStream_t stream)
{
  const float* x    = (const float*)d_in[0];
  const float* Wih  = (const float*)d_in[1];
  const float* Whh  = (const float*)d_in[2];
  const float* bih  = (const float*)d_in[3];
  const float* bhh  = (const float*)d_in[4];
  // d_in[5..8] = dec_* : provably unused by the reference output
  const float* dW   = (const float*)d_in[9];
  const float* db   = (const float*)d_in[10];
  float* out = (float*)d_out;

  unsigned short* Wp    = (unsigned short*)d_ws;               // 2 MB
  unsigned long long* X = (unsigned long long*)(Wp + 1048576); // 131072 u64 (1 MB)
  float* hfp  = (float*)(X + 131072);                          // 131072 f32
  float* cfin = hfp + 131072;                                  // 131072 f32
  float* G    = cfin + 131072;                                 // 524288 f32 (2 MB)

  // Clear BOTH parity buffers: buffer1 = h(-1) (tag 0, payload 0); buffer0
  // cleared so no stale/garbage tag can false-match (replay safety).
  hipMemsetAsync(X, 0, 131072 * sizeof(unsigned long long), stream);
  pack_w<<<512, 256, 0, stream>>>(Whh, Wp);
  enc_persist<<<256, 256, 0, stream>>>(Wp, x, Wih, bih, bhh, X,
                                       hfp, cfin, G, 0);
  decoder<<<64, 256, 0, stream>>>(G, cfin, hfp, Wih, dW, db, out);
}